// Round 13
// baseline (113.884 us; speedup 1.0000x reference)
//
#include <hip/hip_runtime.h>
#include <hip/hip_bf16.h>
#include <stdint.h>

constexpr int NUM_NODES = 120000;
constexpr int Tn = 10;
constexpr int Bb = 64, Rr = 4, Nn = 64, Ii = 64;
constexpr int RSTR  = 147456;   // per-relation Wf stride (bf16 elems)
constexpr int OFF0  = 0;        // L0 w1   [tap2][ct4][ks4][lane64][8]
constexpr int OFF1  = 16384;    // L0 down [ct4][ks4][lane64][8]
constexpr int OFF2  = 24576;    // L0 w2   [tap2][ct4][ks2][lane64][8]
constexpr int OFFL0 = 32768;    // levels  14 x [tap2][ct4][ks2][lane64][8]

// Per-wave private LDS slice (NO cross-wave sharing, NO barriers).
constexpr int XO  = 0;      // X: 20 cols x 256B = 5120
constexpr int H0O = 0;      // aliases X (X dead after p1/p2 reads)
constexpr int H1O = 2048;
constexpr int H2O = 3072;
constexpr int H3O = 4096;   // H3..H6 at +256 each, ends 5120
constexpr int YO  = 5120;   // 20 cols x 128 = 2560
constexpr int TRO = 7680;   // trash: 16 cols x 128 = 2048 (never read)
constexpr int ZO  = 9728;   // 256B zero row
constexpr int WSZ = 9984;   // per-wave bytes; 4 waves = 39936 B

typedef __attribute__((ext_vector_type(8))) short bf16x8;
typedef __attribute__((ext_vector_type(4))) float f32x4;
typedef __attribute__((ext_vector_type(4))) short s16x4;

__device__ __forceinline__ short f2bf(float f) {
  __hip_bfloat16 h = __float2bfloat16(f);
  return *reinterpret_cast<short*>(&h);
}
__device__ __forceinline__ float bf2f(short s) {
  union { unsigned int u; float f; } x;
  x.u = ((unsigned int)(unsigned short)s) << 16;
  return x.f;
}

// ---------------------------------------------------------------------------
// Bake weights into per-lane MFMA A-fragments (bf16). (verified rounds 3-12)
// ---------------------------------------------------------------------------
extern "C" __global__ void prep_kernel(const float* __restrict__ w1_0,
                                       const float* __restrict__ w2_0,
                                       const float* __restrict__ down_w,
                                       const float* __restrict__ w1s,
                                       const float* __restrict__ w2s,
                                       short* __restrict__ Wf) {
  int i0 = blockIdx.x * blockDim.x + threadIdx.x;
  int stride = gridDim.x * blockDim.x;
  for (int e = i0; e < Rr * RSTR; e += stride) {
    int r = e / RSTR, q = e - r * RSTR;
    float v;
    if (q < 16384) {
      int j = q & 7, lane = (q >> 3) & 63, ks = (q >> 9) & 3, ct = (q >> 11) & 3, tap = (q >> 13) & 1;
      int cout = ct * 16 + (lane & 15), cin = ks * 32 + (lane >> 4) * 8 + j;
      v = w1_0[((r * 64 + cout) * 128 + cin) * 2 + tap];
    } else if (q < 24576) {
      int q2 = q - 16384;
      int j = q2 & 7, lane = (q2 >> 3) & 63, ks = (q2 >> 9) & 3, ct = (q2 >> 11) & 3;
      int cout = ct * 16 + (lane & 15), cin = ks * 32 + (lane >> 4) * 8 + j;
      v = down_w[(r * 64 + cout) * 128 + cin];
    } else if (q < 32768) {
      int q2 = q - 24576;
      int j = q2 & 7, lane = (q2 >> 3) & 63, ks = (q2 >> 9) & 1, ct = (q2 >> 10) & 3, tap = (q2 >> 12) & 1;
      int cout = ct * 16 + (lane & 15), cin = ks * 32 + (lane >> 4) * 8 + j;
      v = w2_0[((r * 64 + cout) * 64 + cin) * 2 + tap];
    } else {
      int q2 = q - 32768;
      int lc = q2 >> 13;
      int l = lc >> 1, jw = lc & 1;
      int q3 = q2 & 8191;
      int j = q3 & 7, lane = (q3 >> 3) & 63, ks = (q3 >> 9) & 1, ct = (q3 >> 10) & 3, tap = (q3 >> 12) & 1;
      int cout = ct * 16 + (lane & 15), cin = ks * 32 + (lane >> 4) * 8 + j;
      const float* src = jw ? w2s : w1s;
      v = src[(((r * 7 + l) * 64 + cout) * 64 + cin) * 2 + tap];
    }
    Wf[e] = f2bf(v);
  }
}

// ---------------------------------------------------------------------------
// Wave-independent conv. Tile cols: c = lane&15 -> (u = c>>1 slot-in-tile,
// s = c&1 seq). Wave computes ALL 4 cout-tiles; each B-read feeds 4 MFMAs.
// T1/T0[mt][u] = source slot in src region (-1 -> zero row).
// ---------------------------------------------------------------------------
template <int KSN, int NTAP, int NMT, int ROWB>
__device__ __forceinline__ void conv_wi(const char* __restrict__ wb, int srcOff,
                                        const short* __restrict__ wf1,
                                        const short* __restrict__ wf0,
                                        const float* __restrict__ bias,
                                        const int (&T1)[NMT][8], const int (&T0)[NMT][8],
                                        int lane, f32x4 (&acc)[NMT][4]) {
  const int c16 = (lane >> 4) * 16;
  const int u = (lane & 15) >> 1, s = lane & 1;
#pragma unroll
  for (int ct = 0; ct < 4; ++ct) {
    f32x4 bv;
#pragma unroll
    for (int g = 0; g < 4; ++g) bv[g] = bias[ct * 16 + (lane >> 4) * 4 + g];
#pragma unroll
    for (int mt = 0; mt < NMT; ++mt) acc[mt][ct] = bv;
  }
#pragma unroll
  for (int ks = 0; ks < KSN; ++ks) {
    {
      bf16x8 a1[4];
#pragma unroll
      for (int ct = 0; ct < 4; ++ct)
        a1[ct] = *(const bf16x8*)(wf1 + ((ct * KSN + ks) * 64 + lane) * 8);
#pragma unroll
      for (int mt = 0; mt < NMT; ++mt) {
        int sl = T1[mt][u];
        int col = sl * 2 + s;
        const char* p = (sl < 0)
            ? wb + ZO + ((ks * 64 + c16) ^ (s << 4))
            : wb + srcOff + col * ROWB + ((ks * 64 + c16) ^ ((col & 7) << 4));
        bf16x8 b = *(const bf16x8*)p;
#pragma unroll
        for (int ct = 0; ct < 4; ++ct)
          acc[mt][ct] = __builtin_amdgcn_mfma_f32_16x16x32_bf16(a1[ct], b, acc[mt][ct], 0, 0, 0);
      }
    }
    if (NTAP == 2) {
      bf16x8 a0[4];
#pragma unroll
      for (int ct = 0; ct < 4; ++ct)
        a0[ct] = *(const bf16x8*)(wf0 + ((ct * KSN + ks) * 64 + lane) * 8);
#pragma unroll
      for (int mt = 0; mt < NMT; ++mt) {
        int sl = T0[mt][u];
        int col = sl * 2 + s;
        const char* p = (sl < 0)
            ? wb + ZO + ((ks * 64 + c16) ^ (s << 4))
            : wb + srcOff + col * ROWB + ((ks * 64 + c16) ^ ((col & 7) << 4));
        bf16x8 b = *(const bf16x8*)p;
#pragma unroll
        for (int ct = 0; ct < 4; ++ct)
          acc[mt][ct] = __builtin_amdgcn_mfma_f32_16x16x32_bf16(a0[ct], b, acc[mt][ct], 0, 0, 0);
      }
    }
  }
}

template <int NMT>
__device__ __forceinline__ void store_wi(char* __restrict__ wb, int dstOff,
                                         const int (&OS)[NMT][8], int lane,
                                         const f32x4 (&v)[NMT][4]) {
  const int u = (lane & 15) >> 1, s = lane & 1;
#pragma unroll
  for (int mt = 0; mt < NMT; ++mt) {
    int sl = OS[mt][u];
    int col = sl * 2 + s;
#pragma unroll
    for (int ct = 0; ct < 4; ++ct) {
      int co = ct * 32 + (lane >> 4) * 8;
      char* p = (sl >= 0)
          ? wb + dstOff + col * 128 + (co ^ ((col & 7) << 4))
          : wb + TRO + (u * 2 + s) * 128 + co;
      s16x4 q;
#pragma unroll
      for (int g = 0; g < 4; ++g) q[g] = f2bf(v[mt][ct][g]);
      *(s16x4*)p = q;
    }
  }
}

#define RELU_WI(A, N)                                         \
  _Pragma("unroll") for (int _t = 0; _t < N; ++_t)            \
      _Pragma("unroll") for (int _c = 0; _c < 4; ++_c)        \
          _Pragma("unroll") for (int _g = 0; _g < 4; ++_g)    \
              A[_t][_c][_g] = fmaxf(A[_t][_c][_g], 0.f);

template <int NMT>
__device__ __forceinline__ void resid_wi(const char* __restrict__ wb, int prevOff,
                                         const int (&R)[NMT][8], int lane,
                                         f32x4 (&a)[NMT][4]) {
  const int u = (lane & 15) >> 1, s = lane & 1;
#pragma unroll
  for (int mt = 0; mt < NMT; ++mt) {
    int rs = R[mt][u];
    int col = rs * 2 + s;
#pragma unroll
    for (int ct = 0; ct < 4; ++ct) {
      int co = ct * 32 + (lane >> 4) * 8;
      const char* p = (rs >= 0)
          ? wb + prevOff + col * 128 + (co ^ ((col & 7) << 4))
          : wb + ZO + co;
      s16x4 q = *(const s16x4*)p;
#pragma unroll
      for (int g = 0; g < 4; ++g)
        a[mt][ct][g] = fmaxf(fmaxf(a[mt][ct][g], 0.f) + bf2f(q[g]), 0.f);
    }
  }
}

// ---------------------------------------------------------------------------
// Main: fully wave-independent TCN. Block = 4 waves; wave owns 2 sequences
// end-to-end in a private LDS slice. ZERO __syncthreads. Grid = 2048.
// ---------------------------------------------------------------------------
extern "C" __global__ void __launch_bounds__(256, 4)
tcn_mfma(const float* __restrict__ emb, const int* __restrict__ align_,
         const int* __restrict__ nidx, const int* __restrict__ nmask,
         const float* __restrict__ b1_0, const float* __restrict__ b2_0,
         const float* __restrict__ down_b, const float* __restrict__ b1s,
         const float* __restrict__ b2s, const short* __restrict__ Wf,
         float* __restrict__ P) {
  __shared__ char sm[4 * WSZ];

  const int tid = threadIdx.x;
  const int lane = tid & 63, wv = tid >> 6;
  char* wb = sm + wv * WSZ;
  const int blk = blockIdx.x;
  const int r = blk >> 9;
  const int b = (blk >> 3) & 63, chunk = blk & 7;

  // zero row (wave-local)
  if (lane < 32) *(uint64_t*)(wb + ZO + lane * 8) = 0;

  // ---- wave-local ballot: pick this wave's 2 valid neighbors ----
  int msk = nmask[(b * Rr + r) * Nn + lane];
  unsigned long long bal = __ballot(msk != 0);
  int rank = (int)__popcll(bal & ((1ull << lane) - 1ull));
  int tgt0 = chunk * 8 + 2 * wv;
  unsigned long long m0 = __ballot(msk != 0 && rank == tgt0);
  unsigned long long m1 = __ballot(msk != 0 && rank == tgt0 + 1);
  int n0 = m0 ? (__ffsll((unsigned long long)m0) - 1) : -1;
  int n1 = m1 ? (__ffsll((unsigned long long)m1) - 1) : -1;
  if (n0 < 0 && n1 < 0) {            // wave inactive: zero partial, exit
    P[(blk * 4 + wv) * 64 + lane] = 0.f;
    return;
  }
  const float mk0 = (n0 >= 0) ? 1.f : 0.f;
  const float mk1 = (n1 >= 0) ? 1.f : 0.f;

  // per-(t,s) gather rows, held in lanes 0..19
  int rid = -1;
  if (lane < 20) {
    int t = lane >> 1, sx = lane & 1;
    int n2 = sx ? n1 : n0;
    if (n2 >= 0) {
      int ent = nidx[(b * Rr + r) * Nn + n2];
      int srow = align_[ent * Tn + t];
      rid = (srow >= 0) ? srow : -1;
    }
  }

  // ---- gather: 20 cols x 128 d -> X (b128 swizzled writes) ----
#pragma unroll
  for (int it = 0; it < 5; ++it) {
    int idx = lane + it * 64;
    int col = idx >> 4, d8 = idx & 15;
    int rc = __shfl(rid, col);
    int t = col >> 1;
    bf16x8 p = {0, 0, 0, 0, 0, 0, 0, 0};
    if (rc >= 0) {
      const float* src = emb + ((size_t)(t * NUM_NODES + rc)) * 128 + d8 * 8;
      const float4 v0 = *(const float4*)(src);
      const float4 v1 = *(const float4*)(src + 4);
      p[0] = f2bf(v0.x); p[1] = f2bf(v0.y); p[2] = f2bf(v0.z); p[3] = f2bf(v0.w);
      p[4] = f2bf(v1.x); p[5] = f2bf(v1.y); p[6] = f2bf(v1.z); p[7] = f2bf(v1.w);
    }
    *(bf16x8*)(wb + XO + col * 256 + ((d8 * 16) ^ ((col & 7) << 4))) = p;
  }

  const short* wr = Wf + r * RSTR;

  // ---- maps (r10-verified, re-indexed per 8-slot tiles) ----
  static constexpr int T1p1[2][8] = {{0,1,2,3,4,5,6,7},{8,9,-1,-1,-1,-1,-1,-1}};
  static constexpr int T0p1[2][8] = {{-1,0,1,2,3,4,5,6},{7,8,-1,-1,-1,-1,-1,-1}};
  static constexpr int OSp1[2][8] = {{0,1,2,3,4,5,6,7},{8,9,-1,-1,-1,-1,-1,-1}};
  static constexpr int TDp2[1][8] = {{1,3,5,7,9,-1,-1,-1}};
  static constexpr int T1p3[1][8] = {{1,3,5,7,9,-1,-1,-1}};
  static constexpr int T0p3[1][8] = {{0,2,4,6,8,-1,-1,-1}};
  static constexpr int OSp3[1][8] = {{0,1,2,3,4,-1,-1,-1}};
  static constexpr int T1L1a[1][8] = {{0,1,2,3,4,-1,-1,-1}};
  static constexpr int T0L1a[1][8] = {{-1,0,1,2,3,-1,-1,-1}};
  static constexpr int OSL1a[1][8] = {{0,1,2,3,4,-1,-1,-1}};
  static constexpr int T1L1b[1][8] = {{0,2,4,-1,-1,-1,-1,-1}};
  static constexpr int T0L1b[1][8] = {{-1,1,3,-1,-1,-1,-1,-1}};
  static constexpr int RL1b[1][8]  = {{0,2,4,-1,-1,-1,-1,-1}};
  static constexpr int OSL1b[1][8] = {{0,1,2,-1,-1,-1,-1,-1}};
  static constexpr int T1L2a[1][8] = {{0,1,2,-1,-1,-1,-1,-1}};
  static constexpr int T0L2a[1][8] = {{-1,0,1,-1,-1,-1,-1,-1}};
  static constexpr int OSL2a[1][8] = {{0,1,2,-1,-1,-1,-1,-1}};
  static constexpr int T1L2b[1][8] = {{0,2,-1,-1,-1,-1,-1,-1}};
  static constexpr int T0L2b[1][8] = {{-1,1,-1,-1,-1,-1,-1,-1}};
  static constexpr int RL2b[1][8]  = {{0,2,-1,-1,-1,-1,-1,-1}};
  static constexpr int OSL2b[1][8] = {{0,1,-1,-1,-1,-1,-1,-1}};
  static constexpr int T1L3a[1][8] = {{0,1,-1,-1,-1,-1,-1,-1}};
  static constexpr int T0L3a[1][8] = {{-1,0,-1,-1,-1,-1,-1,-1}};
  static constexpr int OSL3a[1][8] = {{0,1,-1,-1,-1,-1,-1,-1}};
  static constexpr int T1L3b[1][8] = {{1,-1,-1,-1,-1,-1,-1,-1}};
  static constexpr int T0L3b[1][8] = {{0,-1,-1,-1,-1,-1,-1,-1}};
  static constexpr int RL3b[1][8]  = {{1,-1,-1,-1,-1,-1,-1,-1}};
  static constexpr int OS1[1][8]   = {{0,-1,-1,-1,-1,-1,-1,-1}};
  static constexpr int TA[1][8]    = {{0,-1,-1,-1,-1,-1,-1,-1}};

  // ---- p1: Y0 = relu(conv1_0(X)) ----
  {
    f32x4 a[2][4];
    conv_wi<4, 2, 2, 256>(wb, XO, wr + OFF0 + 8192, wr + OFF0, b1_0 + r * 64,
                          T1p1, T0p1, lane, a);
    RELU_WI(a, 2)
    store_wi<2>(wb, YO, OSp1, lane, a);
  }
  // ---- p2: down(X) at odd t, in regs ----
  f32x4 accD[1][4];
  conv_wi<4, 1, 1, 256>(wb, XO, wr + OFF1, wr + OFF1, down_b + r * 64,
                        TDp2, TDp2, lane, accD);
  // ---- p3: H0 = relu(relu(conv2_0(Y0)) + down) ----
  {
    f32x4 a[1][4];
    conv_wi<2, 2, 1, 128>(wb, YO, wr + OFF2 + 4096, wr + OFF2, b2_0 + r * 64,
                          T1p3, T0p3, lane, a);
#pragma unroll
    for (int ct = 0; ct < 4; ++ct)
#pragma unroll
      for (int g = 0; g < 4; ++g)
        a[0][ct][g] = fmaxf(fmaxf(a[0][ct][g], 0.f) + accD[0][ct][g], 0.f);
    store_wi<1>(wb, H0O, OSp3, lane, a);   // overwrites X head (dead)
  }
  // ---- level 1 (d=2) ----
  {
    f32x4 a[1][4];
    const short* wl = wr + OFFL0;
    conv_wi<2, 2, 1, 128>(wb, H0O, wl + 4096, wl, b1s + (r * 7 + 0) * 64,
                          T1L1a, T0L1a, lane, a);
    RELU_WI(a, 1)
    store_wi<1>(wb, YO, OSL1a, lane, a);
  }
  {
    f32x4 a[1][4];
    const short* wl = wr + OFFL0 + 8192;
    conv_wi<2, 2, 1, 128>(wb, YO, wl + 4096, wl, b2s + (r * 7 + 0) * 64,
                          T1L1b, T0L1b, lane, a);
    resid_wi<1>(wb, H0O, RL1b, lane, a);
    store_wi<1>(wb, H1O, OSL1b, lane, a);
  }
  // ---- level 2 (d=4) ----
  {
    f32x4 a[1][4];
    const short* wl = wr + OFFL0 + 16384;
    conv_wi<2, 2, 1, 128>(wb, H1O, wl + 4096, wl, b1s + (r * 7 + 1) * 64,
                          T1L2a, T0L2a, lane, a);
    RELU_WI(a, 1)
    store_wi<1>(wb, YO, OSL2a, lane, a);
  }
  {
    f32x4 a[1][4];
    const short* wl = wr + OFFL0 + 16384 + 8192;
    conv_wi<2, 2, 1, 128>(wb, YO, wl + 4096, wl, b2s + (r * 7 + 1) * 64,
                          T1L2b, T0L2b, lane, a);
    resid_wi<1>(wb, H1O, RL2b, lane, a);
    store_wi<1>(wb, H2O, OSL2b, lane, a);
  }
  // ---- level 3 (d=8) ----
  {
    f32x4 a[1][4];
    const short* wl = wr + OFFL0 + 32768;
    conv_wi<2, 2, 1, 128>(wb, H2O, wl + 4096, wl, b1s + (r * 7 + 2) * 64,
                          T1L3a, T0L3a, lane, a);
    RELU_WI(a, 1)
    store_wi<1>(wb, YO, OSL3a, lane, a);
  }
  {
    f32x4 a[1][4];
    const short* wl = wr + OFFL0 + 32768 + 8192;
    conv_wi<2, 2, 1, 128>(wb, YO, wl + 4096, wl, b2s + (r * 7 + 2) * 64,
                          T1L3b, T0L3b, lane, a);
    resid_wi<1>(wb, H2O, RL3b, lane, a);
    store_wi<1>(wb, H3O, OS1, lane, a);
  }

  // ---- levels 4..7 (single slot t=9, single tap) ----
  f32x4 hfin[4];
#pragma unroll 1
  for (int li = 0; li < 4; ++li) {
    const short* base = wr + OFFL0 + (3 + li) * 16384;
    const int prevOff = H3O + li * 256;
    {
      f32x4 a[1][4];
      conv_wi<2, 1, 1, 128>(wb, prevOff, base + 4096, base + 4096,
                            b1s + (r * 7 + 3 + li) * 64, TA, TA, lane, a);
      RELU_WI(a, 1)
      store_wi<1>(wb, YO, OS1, lane, a);
    }
    {
      f32x4 a[1][4];
      conv_wi<2, 1, 1, 128>(wb, YO, base + 8192 + 4096, base + 8192 + 4096,
                            b2s + (r * 7 + 3 + li) * 64, TA, TA, lane, a);
      resid_wi<1>(wb, prevOff, TA, lane, a);
      if (li < 3) store_wi<1>(wb, prevOff + 256, OS1, lane, a);
#pragma unroll
      for (int ct = 0; ct < 4; ++ct) hfin[ct] = a[0][ct];
    }
  }

  // ---- epilogue: mask + sum this wave's 2 seqs, write P partial ----
  const int c = lane & 15;
  const float mk = (c == 0) ? mk0 : ((c == 1) ? mk1 : 0.f);
#pragma unroll
  for (int ct = 0; ct < 4; ++ct) {
    float s0 = hfin[ct][0] * mk, s1 = hfin[ct][1] * mk;
    float s2 = hfin[ct][2] * mk, s3 = hfin[ct][3] * mk;
    s0 += __shfl_xor(s0, 1);
    s1 += __shfl_xor(s1, 1);
    s2 += __shfl_xor(s2, 1);
    s3 += __shfl_xor(s3, 1);
    if (c == 0) {
      int base = (blk * 4 + wv) * 64 + ct * 16 + (lane >> 4) * 4;
      P[base + 0] = s0;
      P[base + 1] = s1;
      P[base + 2] = s2;
      P[base + 3] = s3;
    }
  }
}

// ---------------------------------------------------------------------------
// out[b][i] = sum_r sum_c (sum over 32 partials P[r][b][k][c]) * rel_w[r][c][i]
// ---------------------------------------------------------------------------
extern "C" __global__ void reduce_kernel(const float* __restrict__ P,
                                         const float* __restrict__ rel_w,
                                         float* __restrict__ out) {
  __shared__ float Sl[Rr * 64];
  int b = blockIdx.x, i = threadIdx.x;
  for (int idx = i; idx < Rr * 64; idx += 64) {
    int rr = idx >> 6, cc = idx & 63;
    float s = 0.f;
    for (int k = 0; k < 32; ++k)
      s += P[(rr * 2048 + b * 32 + k) * 64 + cc];
    Sl[idx] = s;
  }
  __syncthreads();
  float acc = 0.f;
  for (int rr = 0; rr < Rr; ++rr)
#pragma unroll
    for (int cc = 0; cc < 64; ++cc)
      acc += Sl[rr * 64 + cc] * rel_w[(rr * 64 + cc) * Ii + i];
  out[b * Ii + i] = acc;
}

// ---------------------------------------------------------------------------
extern "C" void kernel_launch(void* const* d_in, const int* in_sizes, int n_in,
                              void* d_out, int out_size, void* d_ws, size_t ws_size,
                              hipStream_t stream) {
  const float* emb    = (const float*)d_in[0];
  const float* w1_0   = (const float*)d_in[1];
  const float* b1_0   = (const float*)d_in[2];
  const float* w2_0   = (const float*)d_in[3];
  const float* b2_0   = (const float*)d_in[4];
  const float* down_w = (const float*)d_in[5];
  const float* down_b = (const float*)d_in[6];
  const float* w1s    = (const float*)d_in[7];
  const float* b1s    = (const float*)d_in[8];
  const float* w2s    = (const float*)d_in[9];
  const float* b2s    = (const float*)d_in[10];
  const float* rel_w  = (const float*)d_in[11];
  const int* align_   = (const int*)d_in[12];
  const int* nidx     = (const int*)d_in[13];
  const int* nmask    = (const int*)d_in[14];

  float* P  = (float*)d_ws;                         // 2048*4*64 f32 = 2 MB
  short* Wf = (short*)((char*)d_ws + 2097152);      // 589824 bf16 = 1.15 MB

  prep_kernel<<<768, 256, 0, stream>>>(w1_0, w2_0, down_w, w1s, w2s, Wf);
  tcn_mfma<<<2048, 256, 0, stream>>>(emb, align_, nidx, nmask, b1_0, b2_0, down_b,
                                     b1s, b2s, Wf, P);
  reduce_kernel<<<Bb, 64, 0, stream>>>(P, rel_w, (float*)d_out);
}

// Round 14
// 57.469 us; speedup vs baseline: 1.9817x; 1.9817x over previous
//
#include <hip/hip_runtime.h>
#include <hip/hip_bf16.h>
#include <stdint.h>

constexpr int NUM_NODES = 120000;
constexpr int Tn = 10;
constexpr int Bb = 64, Rr = 4, Nn = 64, Cc = 64, Ii = 64;
constexpr int G = 8;            // sequences per block
constexpr int RSTR  = 147456;   // per-relation Wf stride (bf16 elems)
constexpr int OFF0  = 0;        // L0 w1   [tap2][ct4][ks4][lane64][8]
constexpr int OFF1  = 16384;    // L0 down [ct4][ks4][lane64][8]
constexpr int OFF2  = 24576;    // L0 w2   [tap2][ct4][ks2][lane64][8]
constexpr int OFFL0 = 32768;    // levels  14 x [tap2][ct4][ks2][lane64][8]

// LDS byte offsets (H-chain aliases the dead X region)
constexpr int OFF_X  = 0;       // 80 cols x 256B = 20480
constexpr int OFF_H0 = 0;       // 5 slots x 1024 (valid after level 0)
constexpr int OFF_H1 = 6144;    // 3 slots
constexpr int OFF_H2 = 10240;   // 2 slots
constexpr int OFF_H3 = 12288;   // H3..H6 at +1024 each
constexpr int OFF_Y  = 20480;   // 10 slots x 1024
constexpr int ZOFF   = 30720;   // 256B zero block
constexpr int SMEMB  = 30976;

typedef __attribute__((ext_vector_type(8))) short bf16x8;
typedef __attribute__((ext_vector_type(4))) float f32x4;
typedef __attribute__((ext_vector_type(4))) short s16x4;

__device__ __forceinline__ short f2bf(float f) {
  __hip_bfloat16 h = __float2bfloat16(f);
  return *reinterpret_cast<short*>(&h);
}
__device__ __forceinline__ float bf2f(short s) {
  union { unsigned int u; float f; } x;
  x.u = ((unsigned int)(unsigned short)s) << 16;
  return x.f;
}

// ---------------------------------------------------------------------------
// Bake weights into per-lane MFMA A-fragments (bf16). (verified rounds 3-13)
// ---------------------------------------------------------------------------
extern "C" __global__ void prep_kernel(const float* __restrict__ w1_0,
                                       const float* __restrict__ w2_0,
                                       const float* __restrict__ down_w,
                                       const float* __restrict__ w1s,
                                       const float* __restrict__ w2s,
                                       short* __restrict__ Wf) {
  int i0 = blockIdx.x * blockDim.x + threadIdx.x;
  int stride = gridDim.x * blockDim.x;
  for (int e = i0; e < Rr * RSTR; e += stride) {
    int r = e / RSTR, q = e - r * RSTR;
    float v;
    if (q < 16384) {
      int j = q & 7, lane = (q >> 3) & 63, ks = (q >> 9) & 3, ct = (q >> 11) & 3, tap = (q >> 13) & 1;
      int cout = ct * 16 + (lane & 15), cin = ks * 32 + (lane >> 4) * 8 + j;
      v = w1_0[((r * 64 + cout) * 128 + cin) * 2 + tap];
    } else if (q < 24576) {
      int q2 = q - 16384;
      int j = q2 & 7, lane = (q2 >> 3) & 63, ks = (q2 >> 9) & 3, ct = (q2 >> 11) & 3;
      int cout = ct * 16 + (lane & 15), cin = ks * 32 + (lane >> 4) * 8 + j;
      v = down_w[(r * 64 + cout) * 128 + cin];
    } else if (q < 32768) {
      int q2 = q - 24576;
      int j = q2 & 7, lane = (q2 >> 3) & 63, ks = (q2 >> 9) & 1, ct = (q2 >> 10) & 3, tap = (q2 >> 12) & 1;
      int cout = ct * 16 + (lane & 15), cin = ks * 32 + (lane >> 4) * 8 + j;
      v = w2_0[((r * 64 + cout) * 64 + cin) * 2 + tap];
    } else {
      int q2 = q - 32768;
      int lc = q2 >> 13;
      int l = lc >> 1, jw = lc & 1;
      int q3 = q2 & 8191;
      int j = q3 & 7, lane = (q3 >> 3) & 63, ks = (q3 >> 9) & 1, ct = (q3 >> 10) & 3, tap = (q3 >> 12) & 1;
      int cout = ct * 16 + (lane & 15), cin = ks * 32 + (lane >> 4) * 8 + j;
      const float* src = jw ? w2s : w1s;
      v = src[(((r * 7 + l) * 64 + cout) * 64 + cin) * 2 + tap];
    }
    Wf[e] = f2bf(v);
  }
}

// ---------------------------------------------------------------------------
// Sparse-slot conv pass. Input cols packed slot-major (col = slot*8+seq).
// T1/T0: per-output-slot input-slot maps (-1 => zero row). All static.
// ---------------------------------------------------------------------------
template <int KSN, int NMT, int NTAP, int ROWB>
__device__ __forceinline__ void conv_sp(const char* __restrict__ sm, int srcOff,
                                        const short* __restrict__ wf1,
                                        const short* __restrict__ wf0,
                                        const float* __restrict__ bias,
                                        const int (&T1)[NMT * 2], const int (&T0)[NMT * 2],
                                        int lane, int ct, f32x4 (&acc)[NMT]) {
  const int c16 = (lane >> 4) * 16;
  const int seq = lane & 7;
  const int hi = (lane & 15) >> 3;
  const int sw = seq << 4;
  float bv[4];
#pragma unroll
  for (int g = 0; g < 4; ++g) bv[g] = bias[ct * 16 + (lane >> 4) * 4 + g];
#pragma unroll
  for (int mt = 0; mt < NMT; ++mt) acc[mt] = (f32x4){bv[0], bv[1], bv[2], bv[3]};
  bf16x8 af1[KSN], af0[KSN];
#pragma unroll
  for (int ks = 0; ks < KSN; ++ks)
    af1[ks] = *(const bf16x8*)(wf1 + ((ct * KSN + ks) * 64 + lane) * 8);
  if (NTAP == 2) {
#pragma unroll
    for (int ks = 0; ks < KSN; ++ks)
      af0[ks] = *(const bf16x8*)(wf0 + ((ct * KSN + ks) * 64 + lane) * 8);
  }
#pragma unroll
  for (int mt = 0; mt < NMT; ++mt) {
    int s1 = hi ? T1[2 * mt + 1] : T1[2 * mt];
    const char* p1 = sm + ((s1 < 0) ? ZOFF : srcOff + (s1 * 8 + seq) * ROWB);
#pragma unroll
    for (int ks = 0; ks < KSN; ++ks) {
      bf16x8 b = *(const bf16x8*)(p1 + ((ks * 64 + c16) ^ sw));
      acc[mt] = __builtin_amdgcn_mfma_f32_16x16x32_bf16(af1[ks], b, acc[mt], 0, 0, 0);
    }
    if (NTAP == 2) {
      int s0 = hi ? T0[2 * mt + 1] : T0[2 * mt];
      const char* p0 = sm + ((s0 < 0) ? ZOFF : srcOff + (s0 * 8 + seq) * ROWB);
#pragma unroll
      for (int ks = 0; ks < KSN; ++ks) {
        bf16x8 b = *(const bf16x8*)(p0 + ((ks * 64 + c16) ^ sw));
        acc[mt] = __builtin_amdgcn_mfma_f32_16x16x32_bf16(af0[ks], b, acc[mt], 0, 0, 0);
      }
    }
  }
}

template <int NMT>
__device__ __forceinline__ void store_sp(char* __restrict__ sm, int dstOff, int lane,
                                         int ct, const f32x4 (&v)[NMT]) {
  const int co = ct * 32 + (lane >> 4) * 8;
#pragma unroll
  for (int mt = 0; mt < NMT; ++mt) {
    int oc = 16 * mt + (lane & 15);
    s16x4 p;
#pragma unroll
    for (int g = 0; g < 4; ++g) p[g] = f2bf(v[mt][g]);
    *(s16x4*)(sm + dstOff + oc * 128 + (co ^ ((oc & 7) << 4))) = p;
  }
}

#define RELU_ALL(A, N)                                        \
  _Pragma("unroll") for (int _t = 0; _t < N; ++_t)            \
      _Pragma("unroll") for (int _g = 0; _g < 4; ++_g)        \
          A[_t][_g] = fmaxf(A[_t][_g], 0.f);

// residual: h = relu(relu(acc) + H_prev(bf16 from LDS))
template <int NMT>
__device__ __forceinline__ void resid_sp(const char* __restrict__ sm, int prevOff,
                                         const int (&R)[NMT * 2], int lane, int ct,
                                         f32x4 (&a)[NMT]) {
  const int co = ct * 32 + (lane >> 4) * 8;
  const int seq = lane & 7;
  const int hi = (lane & 15) >> 3;
  const int sw = seq << 4;
#pragma unroll
  for (int mt = 0; mt < NMT; ++mt) {
    int rs = hi ? R[2 * mt + 1] : R[2 * mt];
    const char* p = sm + ((rs < 0) ? ZOFF : prevOff + (rs * 8 + seq) * 128);
    s16x4 q = *(const s16x4*)(p + (co ^ sw));
#pragma unroll
    for (int g = 0; g < 4; ++g)
      a[mt][g] = fmaxf(fmaxf(a[mt][g], 0.f) + bf2f(q[g]), 0.f);
  }
}

// ---------------------------------------------------------------------------
// Main: gather + temporally-sparse TCN (44 cols/seq instead of 150).
// Block = 256 thr = 4 waves (wave = cout-tile of 16), 8 valid sequences.
// launch_bounds(256,5): 5 blocks/CU (31KB LDS x5 = 155KB fits 160KB).
// ---------------------------------------------------------------------------
extern "C" __global__ void __launch_bounds__(256, 5)
tcn_mfma(const float* __restrict__ emb, const int* __restrict__ align_,
         const int* __restrict__ nidx, const int* __restrict__ nmask,
         const float* __restrict__ b1_0, const float* __restrict__ b2_0,
         const float* __restrict__ down_b, const float* __restrict__ b1s,
         const float* __restrict__ b2s, const short* __restrict__ Wf,
         float* __restrict__ P) {
  __shared__ char sm[SMEMB];
  __shared__ int rowid[80];
  __shared__ float mkv[G];
  __shared__ int mapg[G];
  __shared__ int totv;

  const int tid = threadIdx.x;
  const int lane = tid & 63, ct = tid >> 6;
  const int blk = blockIdx.x;
  const int r = blk >> 9;
  const int blkr = blk & 511;
  const int b = blkr >> 3, chunk = blkr & 7;

  // ---- ballot compaction of this (b,r)'s valid neighbors ----
  if (tid < 64) {
    int n = tid;
    int msk = nmask[(b * Rr + r) * Nn + n];
    unsigned long long bal = __ballot(msk != 0);
    if (tid < G) mapg[tid] = -1;
    if (tid == 0) totv = (int)__popcll(bal);
    int rank = (int)__popcll(bal & ((1ull << n) - 1ull));
    if (msk != 0 && rank >= chunk * G && rank < chunk * G + G)
      mapg[rank - chunk * G] = n;
  }
  if (tid >= 192 && tid < 224) *(uint64_t*)(sm + ZOFF + (tid - 192) * 8) = 0;
  __syncthreads();
  if (chunk * G >= totv) {           // inactive block: zero partial, exit
    if (tid < 64) P[((r * Bb + b) * 8 + chunk) * 64 + tid] = 0.f;
    return;
  }

  // col = t*8 + seq  (slot-major packing)
  if (tid < 80) {
    int t = tid >> 3, seq = tid & 7;
    int n2 = mapg[seq];
    int s = -1;
    if (n2 >= 0) {
      int ent = nidx[(b * Rr + r) * Nn + n2];
      s = align_[ent * Tn + t];
    }
    rowid[tid] = (n2 >= 0 && s >= 0) ? s : -1;
    if (t == 0) mkv[seq] = (n2 >= 0) ? 1.0f : 0.0f;
  }
  __syncthreads();

  // gather: 80 cols x 128 d, f32 -> bf16, b128 swizzled LDS writes
#pragma unroll
  for (int it = 0; it < 5; ++it) {
    int idx = tid + it * 256;
    int col = idx >> 4, d8 = idx & 15;
    int row = rowid[col];
    int t = col >> 3;
    bf16x8 p = {0, 0, 0, 0, 0, 0, 0, 0};
    if (row >= 0) {
      const float* src = emb + ((size_t)t * NUM_NODES + row) * 128 + d8 * 8;
      const float4 v0 = *(const float4*)(src);
      const float4 v1 = *(const float4*)(src + 4);
      p[0] = f2bf(v0.x); p[1] = f2bf(v0.y); p[2] = f2bf(v0.z); p[3] = f2bf(v0.w);
      p[4] = f2bf(v1.x); p[5] = f2bf(v1.y); p[6] = f2bf(v1.z); p[7] = f2bf(v1.w);
    }
    *(bf16x8*)(sm + OFF_X + col * 256 + ((d8 * 16) ^ ((col & 7) << 4))) = p;
  }
  __syncthreads();

  const short* wr = Wf + r * RSTR;

  // ---- pass1: Y0 = relu(conv1_0(X)), all t ----
  {
    constexpr int T1[10] = {0, 1, 2, 3, 4, 5, 6, 7, 8, 9};
    constexpr int T0[10] = {-1, 0, 1, 2, 3, 4, 5, 6, 7, 8};
    f32x4 a[5];
    conv_sp<4, 5, 2, 256>(sm, OFF_X, wr + OFF0 + 8192, wr + OFF0, b1_0 + r * 64,
                          T1, T0, lane, ct, a);
    RELU_ALL(a, 5)
    store_sp<5>(sm, OFF_Y, lane, ct, a);
  }
  // ---- pass2: down(X) at odd t, carried in regs ----
  f32x4 accD[3];
  {
    constexpr int TD[6] = {1, 3, 5, 7, 9, 9};
    conv_sp<4, 3, 1, 256>(sm, OFF_X, wr + OFF1, wr + OFF1, down_b + r * 64,
                          TD, TD, lane, ct, accD);
  }
  __syncthreads();
  // ---- pass3: H0 = relu(relu(conv2_0(Y0)) + down) at odd t ----
  {
    constexpr int T1[6] = {1, 3, 5, 7, 9, 9};
    constexpr int T0[6] = {0, 2, 4, 6, 8, 8};
    f32x4 a[3];
    conv_sp<2, 3, 2, 128>(sm, OFF_Y, wr + OFF2 + 4096, wr + OFF2, b2_0 + r * 64,
                          T1, T0, lane, ct, a);
#pragma unroll
    for (int mt = 0; mt < 3; ++mt)
#pragma unroll
      for (int g = 0; g < 4; ++g)
        a[mt][g] = fmaxf(fmaxf(a[mt][g], 0.f) + accD[mt][g], 0.f);
    store_sp<3>(sm, OFF_H0, lane, ct, a);
  }
  __syncthreads();
  // ---- level 1 (d=2): Y1 at H0-slots; H1 at [1,5,9] ----
  {
    constexpr int T1[6] = {0, 1, 2, 3, 4, 4};
    constexpr int T0[6] = {-1, 0, 1, 2, 3, 3};
    f32x4 a[3];
    const short* wb = wr + OFFL0;
    conv_sp<2, 3, 2, 128>(sm, OFF_H0, wb + 4096, wb, b1s + (r * 7 + 0) * 64,
                          T1, T0, lane, ct, a);
    RELU_ALL(a, 3)
    store_sp<3>(sm, OFF_Y, lane, ct, a);
  }
  __syncthreads();
  {
    constexpr int T1[4] = {0, 2, 4, 4};
    constexpr int T0[4] = {-1, 1, 3, 3};
    constexpr int R[4] = {0, 2, 4, 4};
    f32x4 a[2];
    const short* wb = wr + OFFL0 + 8192;
    conv_sp<2, 2, 2, 128>(sm, OFF_Y, wb + 4096, wb, b2s + (r * 7 + 0) * 64,
                          T1, T0, lane, ct, a);
    resid_sp<2>(sm, OFF_H0, R, lane, ct, a);
    store_sp<2>(sm, OFF_H1, lane, ct, a);
  }
  __syncthreads();
  // ---- level 2 (d=4): Y2 at [1,5,9]; H2 at [1,9] ----
  {
    constexpr int T1[4] = {0, 1, 2, 2};
    constexpr int T0[4] = {-1, 0, 1, 1};
    f32x4 a[2];
    const short* wb = wr + OFFL0 + 16384;
    conv_sp<2, 2, 2, 128>(sm, OFF_H1, wb + 4096, wb, b1s + (r * 7 + 1) * 64,
                          T1, T0, lane, ct, a);
    RELU_ALL(a, 2)
    store_sp<2>(sm, OFF_Y, lane, ct, a);
  }
  __syncthreads();
  {
    constexpr int T1[2] = {0, 2};
    constexpr int T0[2] = {-1, 1};
    constexpr int R[2] = {0, 2};
    f32x4 a[1];
    const short* wb = wr + OFFL0 + 16384 + 8192;
    conv_sp<2, 1, 2, 128>(sm, OFF_Y, wb + 4096, wb, b2s + (r * 7 + 1) * 64,
                          T1, T0, lane, ct, a);
    resid_sp<1>(sm, OFF_H1, R, lane, ct, a);
    store_sp<1>(sm, OFF_H2, lane, ct, a);
  }
  __syncthreads();
  // ---- level 3 (d=8): Y3 at [1,9]; H3 at [9] ----
  {
    constexpr int T1[2] = {0, 1};
    constexpr int T0[2] = {-1, 0};
    f32x4 a[1];
    const short* wb = wr + OFFL0 + 32768;
    conv_sp<2, 1, 2, 128>(sm, OFF_H2, wb + 4096, wb, b1s + (r * 7 + 2) * 64,
                          T1, T0, lane, ct, a);
    RELU_ALL(a, 1)
    store_sp<1>(sm, OFF_Y, lane, ct, a);
  }
  __syncthreads();
  {
    constexpr int T1[2] = {1, 1};
    constexpr int T0[2] = {0, 0};
    constexpr int R[2] = {1, 1};
    f32x4 a[1];
    const short* wb = wr + OFFL0 + 32768 + 8192;
    conv_sp<2, 1, 2, 128>(sm, OFF_Y, wb + 4096, wb, b2s + (r * 7 + 2) * 64,
                          T1, T0, lane, ct, a);
    resid_sp<1>(sm, OFF_H2, R, lane, ct, a);
    store_sp<1>(sm, OFF_H3, lane, ct, a);
  }
  __syncthreads();

  // ---- levels 4..7 (d>=16, single tap, single slot t=9) ----
  f32x4 hfin[1];
  static constexpr int TA[2] = {0, 0};
#pragma unroll 1
  for (int li = 0; li < 4; ++li) {
    const short* base = wr + OFFL0 + (3 + li) * 16384;
    const int prevOff = OFF_H3 + li * 1024;
    {
      f32x4 a[1];
      conv_sp<2, 1, 1, 128>(sm, prevOff, base + 4096, base + 4096,
                            b1s + (r * 7 + 3 + li) * 64, TA, TA, lane, ct, a);
      RELU_ALL(a, 1)
      store_sp<1>(sm, OFF_Y, lane, ct, a);
    }
    __syncthreads();
    {
      f32x4 a[1];
      conv_sp<2, 1, 1, 128>(sm, OFF_Y, base + 8192 + 4096, base + 8192 + 4096,
                            b2s + (r * 7 + 3 + li) * 64, TA, TA, lane, ct, a);
      resid_sp<1>(sm, prevOff, TA, lane, ct, a);
      if (li < 3) store_sp<1>(sm, prevOff + 1024, lane, ct, a);
      hfin[0] = a[0];
    }
    __syncthreads();
  }

  // ---- epilogue: mask + reduce over 8 sequences (lanes 0-7 of each group) ----
  float mk = ((lane & 15) < 8) ? mkv[lane & 7] : 0.f;
  float s0 = hfin[0][0] * mk, s1 = hfin[0][1] * mk, s2 = hfin[0][2] * mk, s3 = hfin[0][3] * mk;
#pragma unroll
  for (int m2 = 1; m2 <= 4; m2 <<= 1) {
    s0 += __shfl_xor(s0, m2);
    s1 += __shfl_xor(s1, m2);
    s2 += __shfl_xor(s2, m2);
    s3 += __shfl_xor(s3, m2);
  }
  if ((lane & 15) == 0) {
    int base = ((r * Bb + b) * 8 + chunk) * 64 + ct * 16 + (lane >> 4) * 4;
    P[base + 0] = s0;
    P[base + 1] = s1;
    P[base + 2] = s2;
    P[base + 3] = s3;
  }
}

// ---------------------------------------------------------------------------
// out[b][i] = sum_r sum_c (sum_p P[r][b][p][c]) * rel_w[r][c][i]
// ---------------------------------------------------------------------------
extern "C" __global__ void reduce_kernel(const float* __restrict__ P,
                                         const float* __restrict__ rel_w,
                                         float* __restrict__ out) {
  __shared__ float Sl[Rr * Cc];
  int b = blockIdx.x, i = threadIdx.x;
  for (int idx = i; idx < Rr * Cc; idx += 64) {
    int rr = idx >> 6, cc = idx & 63;
    float s = 0.f;
    for (int p = 0; p < 8; ++p) s += P[((rr * Bb + b) * 8 + p) * 64 + cc];
    Sl[idx] = s;
  }
  __syncthreads();
  float acc = 0.f;
  for (int r = 0; r < Rr; ++r)
#pragma unroll
    for (int cc = 0; cc < 64; ++cc)
      acc += Sl[r * Cc + cc] * rel_w[(r * Cc + cc) * Ii + i];
  out[b * Ii + i] = acc;
}

// ---------------------------------------------------------------------------
extern "C" void kernel_launch(void* const* d_in, const int* in_sizes, int n_in,
                              void* d_out, int out_size, void* d_ws, size_t ws_size,
                              hipStream_t stream) {
  const float* emb    = (const float*)d_in[0];
  const float* w1_0   = (const float*)d_in[1];
  const float* b1_0   = (const float*)d_in[2];
  const float* w2_0   = (const float*)d_in[3];
  const float* b2_0   = (const float*)d_in[4];
  const float* down_w = (const float*)d_in[5];
  const float* down_b = (const float*)d_in[6];
  const float* w1s    = (const float*)d_in[7];
  const float* b1s    = (const float*)d_in[8];
  const float* w2s    = (const float*)d_in[9];
  const float* b2s    = (const float*)d_in[10];
  const float* rel_w  = (const float*)d_in[11];
  const int* align_   = (const int*)d_in[12];
  const int* nidx     = (const int*)d_in[13];
  const int* nmask    = (const int*)d_in[14];

  float* P  = (float*)d_ws;                       // 4*64*8*64 f32 = 512 KB
  short* Wf = (short*)((char*)d_ws + 524288);     // 589824 bf16 = 1.15 MB

  prep_kernel<<<768, 256, 0, stream>>>(w1_0, w2_0, down_w, w1s, w2s, Wf);
  tcn_mfma<<<2048, 256, 0, stream>>>(emb, align_, nidx, nmask, b1_0, b2_0, down_b,
                                     b1s, b2s, Wf, P);
  reduce_kernel<<<Bb, Cc, 0, stream>>>(P, rel_w, (float*)d_out);
}